// Round 4
// baseline (157.348 us; speedup 1.0000x reference)
//
#include <hip/hip_runtime.h>

// Problem constants (fixed by the reference's setup_inputs)
#define IN_F   256
#define N_ASS  4096
#define OUT_F  256
#define BATCH  128
#define ASS0   256      // first associative node index
#define OUT0   4352     // first output node index (IN_F + N_ASS)
#define SPLITK 32
#define MONO_BLOCKS 256
#define NTHR   256

// ws layout (float offsets):
//   W1T : [IN_F=256][N_ASS=4096] @ 0        (4 MB)  input->assoc, SRC-major ("NN" B operand)
//         -- aliased as P[SPLITK][BATCH][OUT_F] after GEMM1 (exactly 1M floats)
//   W2T : [N_ASS=4096][OUT_F=256] @ 1M      (4 MB)  assoc->output, SRC-major
//   acc : [BATCH=128][N_ASS=4096] @ 2M      (2 MB)
//   cnt : int barrier counters    @ 3M floats
#define OFF_W2T (1024*1024)
#define OFF_ACC (2*1024*1024)
#define OFF_CNT (3*1024*1024)

// Node 1: zero W1T+W2T (2M floats) + barrier counters. Grid must be 2048x256.
__global__ __launch_bounds__(256) void prep_kernel(float* __restrict__ ws) {
    int i = blockIdx.x * blockDim.x + threadIdx.x;
    ((float4*)ws)[i] = make_float4(0.f, 0.f, 0.f, 0.f);   // 524288 float4 = 8 MB
    if (blockIdx.x == 0) ((int*)(ws + OFF_CNT))[threadIdx.x] = 0;
}

// Software grid barrier: 256 co-resident blocks (1/CU on 256 CUs; tiny footprint).
// Release fence -> device-scope arrive -> acquire-load spin (bounded) -> acquire fence.
__device__ __forceinline__ void grid_bar(int* cnt, int nblk) {
    __syncthreads();
    if (threadIdx.x == 0) {
        __threadfence();  // release: write back dirty L2 (cross-XCD visibility)
        __hip_atomic_fetch_add(cnt, 1, __ATOMIC_RELAXED, __HIP_MEMORY_SCOPE_AGENT);
        int iters = 0;
        while (__hip_atomic_load(cnt, __ATOMIC_ACQUIRE, __HIP_MEMORY_SCOPE_AGENT) < nblk) {
            if (++iters > (1 << 22)) break;   // failsafe: wrong answer beats a hang
            __builtin_amdgcn_s_sleep(1);
        }
    }
    __syncthreads();
    __threadfence();      // acquire side for every thread (invalidate stale cached lines)
}

// Node 2: scatter -> bar -> GEMM1 -> bar -> GEMM2(split-K partials) -> bar -> reduce.
__global__ __launch_bounds__(256) void mono_kernel(
        const float* __restrict__ x,
        const float* __restrict__ w_in, const float* __restrict__ w_ass,
        const int* __restrict__ in_src, const int* __restrict__ in_dst,
        const int* __restrict__ a_src,  const int* __restrict__ a_dst,
        int E1, int E2,
        float* __restrict__ ws, float* __restrict__ out) {
    float* W1T = ws;
    float* W2T = ws + OFF_W2T;
    float* acc = ws + OFF_ACC;
    float* P   = ws;                       // alias: W1T dead after GEMM1
    int*   cnt = (int*)(ws + OFF_CNT);

    __shared__ __align__(16) float As[16][68];
    __shared__ __align__(16) float Bs[16][68];

    const int tid = threadIdx.x;
    const int bid = blockIdx.x;

    // ---- phase A: scatter both edge lists into pre-zeroed W1T/W2T ----
    // (src,dst) pairs unique -> plain stores; zeroing happened in prep (prior node).
    for (int e = bid * NTHR + tid; e < E1 + E2; e += MONO_BLOCKS * NTHR) {
        if (e < E1) {
            W1T[in_src[e] * N_ASS + (in_dst[e] - ASS0)] = w_in[e];
        } else {
            int i = e - E1;
            int d = a_dst[i];
            if (d >= OUT0)  // only edges into output nodes affect the result
                W2T[(a_src[i] - ASS0) * OUT_F + (d - OUT0)] = w_ass[i];
        }
    }
    grid_bar(cnt + 0, MONO_BLOCKS);

    // ---- phase B: GEMM1 (NN): acc[128][4096] = x[128][256] @ W1T[256][4096] ----
    {
        const int tx = tid & 15, ty = tid >> 4;
        const int m0 = (bid & 3) * 32, n0 = (bid >> 2) * 64;
        const int lrA = tid >> 2, lcA = (tid & 3) * 4;   // A loader (rows 0..63; use <32)
        const int lrB = tid >> 4, lcB = (tid & 15) * 4;  // B loader: 16 rows x 64 cols
        const bool hA = lrA < 32;
        float c[2][4] = {};
        for (int k0 = 0; k0 < IN_F; k0 += 16) {
            float4 av, bv;
            if (hA) av = *(const float4*)(x + (size_t)(m0 + lrA) * IN_F + k0 + lcA);
            bv = *(const float4*)(W1T + (size_t)(k0 + lrB) * N_ASS + n0 + lcB);
            __syncthreads();
            if (hA) {
                As[lcA + 0][lrA] = av.x; As[lcA + 1][lrA] = av.y;
                As[lcA + 2][lrA] = av.z; As[lcA + 3][lrA] = av.w;
            }
            *(float4*)&Bs[lrB][lcB] = bv;
            __syncthreads();
            #pragma unroll
            for (int k = 0; k < 16; ++k) {
                float4 b4 = *(const float4*)&Bs[k][tx * 4];
                float a0 = As[k][ty * 2], a1 = As[k][ty * 2 + 1];
                c[0][0] = fmaf(a0, b4.x, c[0][0]); c[0][1] = fmaf(a0, b4.y, c[0][1]);
                c[0][2] = fmaf(a0, b4.z, c[0][2]); c[0][3] = fmaf(a0, b4.w, c[0][3]);
                c[1][0] = fmaf(a1, b4.x, c[1][0]); c[1][1] = fmaf(a1, b4.y, c[1][1]);
                c[1][2] = fmaf(a1, b4.z, c[1][2]); c[1][3] = fmaf(a1, b4.w, c[1][3]);
            }
        }
        #pragma unroll
        for (int i = 0; i < 2; ++i) {
            float4 v = make_float4(c[i][0], c[i][1], c[i][2], c[i][3]);
            *(float4*)&acc[(size_t)(m0 + ty * 2 + i) * N_ASS + n0 + tx * 4] = v;
        }
    }
    grid_bar(cnt + 16, MONO_BLOCKS);

    // ---- phase C: GEMM2 (NN, split-K): P[z][128][256] = acc[:,zk] @ W2T[zk][:] ----
    {
        const int tx = tid & 15, ty = tid >> 4;
        const int z = bid >> 3, q = bid & 7;
        const int m0 = (q & 1) * 64, n0 = (q >> 1) * 64;
        const int kBeg = z * (N_ASS / SPLITK);
        const int lrA = tid >> 2, lcA = (tid & 3) * 4;   // A loader: 64 rows x 16 cols
        const int lrB = tid >> 4, lcB = (tid & 15) * 4;  // B loader: 16 rows x 64 cols
        float c[4][4] = {};
        for (int k0 = kBeg; k0 < kBeg + N_ASS / SPLITK; k0 += 16) {
            float4 av = *(const float4*)(acc + (size_t)(m0 + lrA) * N_ASS + k0 + lcA);
            float4 bv = *(const float4*)(W2T + (size_t)(k0 + lrB) * OUT_F + n0 + lcB);
            __syncthreads();
            As[lcA + 0][lrA] = av.x; As[lcA + 1][lrA] = av.y;
            As[lcA + 2][lrA] = av.z; As[lcA + 3][lrA] = av.w;
            *(float4*)&Bs[lrB][lcB] = bv;
            __syncthreads();
            #pragma unroll
            for (int k = 0; k < 16; ++k) {
                float4 b4 = *(const float4*)&Bs[k][tx * 4];
                float4 a4 = *(const float4*)&As[k][ty * 4];
                float a[4] = {a4.x, a4.y, a4.z, a4.w};
                #pragma unroll
                for (int i = 0; i < 4; ++i) {
                    c[i][0] = fmaf(a[i], b4.x, c[i][0]);
                    c[i][1] = fmaf(a[i], b4.y, c[i][1]);
                    c[i][2] = fmaf(a[i], b4.z, c[i][2]);
                    c[i][3] = fmaf(a[i], b4.w, c[i][3]);
                }
            }
        }
        #pragma unroll
        for (int i = 0; i < 4; ++i) {
            float4 v = make_float4(c[i][0], c[i][1], c[i][2], c[i][3]);
            *(float4*)&P[(size_t)z * (BATCH * OUT_F) +
                         (size_t)(m0 + ty * 4 + i) * OUT_F + n0 + tx * 4] = v;
        }
    }
    grid_bar(cnt + 32, MONO_BLOCKS);

    // ---- phase D: reduce split-K partials -> out ----
    {
        int g = bid * NTHR + tid;
        if (g < BATCH * OUT_F) {
            float s = 0.f;
            #pragma unroll
            for (int z2 = 0; z2 < SPLITK; ++z2) s += P[(size_t)z2 * (BATCH * OUT_F) + g];
            out[g] = s;
        }
    }
}

extern "C" void kernel_launch(void* const* d_in, const int* in_sizes, int n_in,
                              void* d_out, int out_size, void* d_ws, size_t ws_size,
                              hipStream_t stream) {
    const float* x      = (const float*)d_in[0];
    const float* w_in   = (const float*)d_in[1];
    const float* w_ass  = (const float*)d_in[2];
    const int*   in_src = (const int*)d_in[3];
    const int*   in_dst = (const int*)d_in[4];
    const int*   a_src  = (const int*)d_in[5];
    const int*   a_dst  = (const int*)d_in[6];
    const int E1 = in_sizes[3];
    const int E2 = in_sizes[5];

    float* ws  = (float*)d_ws;
    float* out = (float*)d_out;

    // Node 1: zero dense weights (8 MB = 524288 float4) + barrier counters
    prep_kernel<<<2048, 256, 0, stream>>>(ws);

    // Node 2: everything else, with internal grid barriers (256 blocks = 1/CU)
    mono_kernel<<<MONO_BLOCKS, NTHR, 0, stream>>>(x, w_in, w_ass, in_src, in_dst,
                                                  a_src, a_dst, E1, E2, ws, out);
}

// Round 5
// 50.664 us; speedup vs baseline: 3.1057x; 3.1057x over previous
//
#include <hip/hip_runtime.h>

// Problem constants (fixed by the reference's setup_inputs, seed 0)
#define IN_F   256
#define N_ASS  4096
#define OUT_F  256
#define BATCH  128
#define ASS0   256      // first associative node index
#define OUT0   4352     // first output node index
#define SPLITK 32
#define MN_OUT (BATCH * OUT_F)   // 16384

// ws layout (float offsets), no aliasing:
//   W1T @ 0      : [IN_F=256][N_ASS=4096]  input->assoc, src-major (4 MB)
//   W2T @ 1M     : [N_ASS=4096][OUT_F=256] assoc->output, src-major (4 MB)
//   acc @ 2M     : [BATCH=128][N_ASS=4096] hop-1 activations (2 MB)
//   P   @ 2.5M   : [SPLITK=32][BATCH*OUT_F] split-K partials (2 MB)
#define OFF_W2T (1024 * 1024)
#define OFF_ACC (2 * 1024 * 1024)
#define OFF_P   (2 * 1024 * 1024 + 512 * 1024)

__device__ __forceinline__ int lower_bound(const int* __restrict__ a, int n, int v) {
    int lo = 0, hi = n;
    while (lo < hi) { int mid = (lo + hi) >> 1; if (a[mid] < v) lo = mid + 1; else hi = mid; }
    return lo;
}

// One node: zero + scatter, ordering resolved per-block (rows owned by block).
// Edge lists are sorted by src (np.nonzero row-major) -> contiguous ranges.
// Blocks 0..255: one W1T row each. Blocks 256..767: eight W2T rows each.
__global__ __launch_bounds__(256) void build_kernel(
        const int* __restrict__ in_src, const int* __restrict__ in_dst,
        const float* __restrict__ w_in, int E1,
        const int* __restrict__ a_src, const int* __restrict__ a_dst,
        const float* __restrict__ w_ass, int E2,
        float* __restrict__ W1T, float* __restrict__ W2T) {
    const int tid = threadIdx.x;
    const int bid = blockIdx.x;
    const float4 z4 = make_float4(0.f, 0.f, 0.f, 0.f);

    if (bid < 256) {
        const int r = bid;                       // input-neuron row
        float4* row4 = (float4*)(W1T + (size_t)r * N_ASS);
        #pragma unroll
        for (int i = 0; i < 4; ++i) row4[tid + 256 * i] = z4;   // 4096 floats
        const int s = lower_bound(in_src, E1, r);
        const int e = lower_bound(in_src, E1, r + 1);
        __syncthreads();
        for (int i = s + tid; i < e; i += 256)
            W1T[(size_t)r * N_ASS + (in_dst[i] - ASS0)] = w_in[i];
    } else {
        const int r0 = (bid - 256) * 8;          // assoc-relative row group
        float4* row4 = (float4*)(W2T + (size_t)r0 * OUT_F);
        #pragma unroll
        for (int i = 0; i < 2; ++i) row4[tid + 256 * i] = z4;   // 2048 floats
        const int lo = lower_bound(a_src, E2, r0 + ASS0);
        const int hi = lower_bound(a_src, E2, r0 + 8 + ASS0);
        __syncthreads();
        for (int i = lo + tid; i < hi; i += 256) {
            const int d = a_dst[i];
            if (d >= OUT0)   // only edges into output nodes affect the result
                W2T[(size_t)(a_src[i] - ASS0) * OUT_F + (d - OUT0)] = w_ass[i];
        }
    }
}

// C(+z-slice)[M_][N_] = A[M_][lda] (cols kBeg..) @ B[KCHUNK rows][N_], NN layout.
// BM=BN=32, BK=64, 256 threads, 2x2 micro-tile, register-prefetched K loop.
template<int M_, int N_, int KCHUNK>
__global__ __launch_bounds__(256) void gemm_nn(const float* __restrict__ A, int lda,
                                               const float* __restrict__ B,
                                               float* __restrict__ C) {
    constexpr int ITERS = KCHUNK / 64;
    __shared__ __align__(16) float As[32][68];   // [m][k]
    __shared__ __align__(16) float Bs[64][36];   // [k][n]

    const int tid = threadIdx.x;
    const int m0 = blockIdx.x * 32;
    const int n0 = blockIdx.y * 32;
    const int kBeg = blockIdx.z * KCHUNK;

    float4 areg[2], breg[2];
    #pragma unroll
    for (int r = 0; r < 2; ++r) {
        const int j = tid + r * 256;
        areg[r] = *(const float4*)(A + (size_t)(m0 + (j >> 4)) * lda + kBeg + (j & 15) * 4);
        breg[r] = *(const float4*)(B + (size_t)(kBeg + (j >> 3)) * N_ + n0 + (j & 7) * 4);
    }

    const int ty2 = (tid >> 4) * 2;
    const int tx2 = (tid & 15) * 2;
    float c00 = 0.f, c01 = 0.f, c10 = 0.f, c11 = 0.f;

    for (int it = 0; it < ITERS; ++it) {
        if (it) __syncthreads();
        #pragma unroll
        for (int r = 0; r < 2; ++r) {
            const int j = tid + r * 256;
            *(float4*)&As[j >> 4][(j & 15) * 4] = areg[r];
            *(float4*)&Bs[j >> 3][(j & 7) * 4] = breg[r];
        }
        __syncthreads();
        if (it + 1 < ITERS) {
            const int k0 = kBeg + (it + 1) * 64;
            #pragma unroll
            for (int r = 0; r < 2; ++r) {
                const int j = tid + r * 256;
                areg[r] = *(const float4*)(A + (size_t)(m0 + (j >> 4)) * lda + k0 + (j & 15) * 4);
                breg[r] = *(const float4*)(B + (size_t)(k0 + (j >> 3)) * N_ + n0 + (j & 7) * 4);
            }
        }
        #pragma unroll
        for (int kk = 0; kk < 64; kk += 4) {
            const float4 a0 = *(const float4*)&As[ty2][kk];
            const float4 a1 = *(const float4*)&As[ty2 + 1][kk];
            #pragma unroll
            for (int u = 0; u < 4; ++u) {
                const float2 b = *(const float2*)&Bs[kk + u][tx2];
                const float av0 = ((const float*)&a0)[u];
                const float av1 = ((const float*)&a1)[u];
                c00 = fmaf(av0, b.x, c00); c01 = fmaf(av0, b.y, c01);
                c10 = fmaf(av1, b.x, c10); c11 = fmaf(av1, b.y, c11);
            }
        }
    }

    float* Cb = C + (size_t)blockIdx.z * (M_ * N_);
    *(float2*)&Cb[(size_t)(m0 + ty2)     * N_ + n0 + tx2] = make_float2(c00, c01);
    *(float2*)&Cb[(size_t)(m0 + ty2 + 1) * N_ + n0 + tx2] = make_float2(c10, c11);
}

// out[g] = sum_z P[z][g] — fixed order, deterministic.
__global__ __launch_bounds__(128) void reduce_kernel(const float* __restrict__ P,
                                                     float* __restrict__ out) {
    const int g = blockIdx.x * 128 + threadIdx.x;
    float s = 0.f;
    #pragma unroll
    for (int z = 0; z < SPLITK; ++z) s += P[(size_t)z * MN_OUT + g];
    out[g] = s;
}

extern "C" void kernel_launch(void* const* d_in, const int* in_sizes, int n_in,
                              void* d_out, int out_size, void* d_ws, size_t ws_size,
                              hipStream_t stream) {
    const float* x      = (const float*)d_in[0];
    const float* w_in   = (const float*)d_in[1];
    const float* w_ass  = (const float*)d_in[2];
    const int*   in_src = (const int*)d_in[3];
    const int*   in_dst = (const int*)d_in[4];
    const int*   a_src  = (const int*)d_in[5];
    const int*   a_dst  = (const int*)d_in[6];
    const int E1 = in_sizes[3];
    const int E2 = in_sizes[5];

    float* ws  = (float*)d_ws;
    float* W1T = ws;
    float* W2T = ws + OFF_W2T;
    float* acc = ws + OFF_ACC;
    float* P   = ws + OFF_P;
    float* out = (float*)d_out;

    // 1) build dense W1T/W2T (zero + scatter fused; per-block row ownership)
    build_kernel<<<768, 256, 0, stream>>>(in_src, in_dst, w_in, E1,
                                          a_src, a_dst, w_ass, E2, W1T, W2T);

    // 2) GEMM1: acc[128][4096] = x[128][256] @ W1T[256][4096]   (512 blocks)
    gemm_nn<BATCH, N_ASS, IN_F><<<dim3(4, 128, 1), 256, 0, stream>>>(x, IN_F, W1T, acc);

    // 3) GEMM2: P[z][128][256] = acc[:, z-chunk] @ W2T[z-chunk][:]  (1024 blocks)
    gemm_nn<BATCH, OUT_F, N_ASS / SPLITK><<<dim3(4, 8, SPLITK), 256, 0, stream>>>(acc, N_ASS, W2T, P);

    // 4) out = sum of split-K partials (fixed order)
    reduce_kernel<<<MN_OUT / 128, 128, 0, stream>>>(P, out);
}